// Round 12
// baseline (207.518 us; speedup 1.0000x reference)
//
#include <hip/hip_runtime.h>
#include <math.h>

#define DIMD 768
#define DSTATE 64
#define DINNER 1536
#define DTRANK 48
#define BATCH 2
#define SEQL 1024
#define NTOK (BATCH*SEQL)
#define XDBL_P 192              // padded x_dbl row stride; cols 48..175 = B/C interleaved
#define EPSV 1e-5f

typedef __attribute__((ext_vector_type(8))) short bf16x8;
typedef __attribute__((ext_vector_type(4))) float f32x4;

__device__ inline short f2bf(float f) {             // RTNE f32 -> bf16
  unsigned u = __float_as_uint(f);
  u = u + 0x7FFFu + ((u >> 16) & 1u);
  return (short)(u >> 16);
}

// ---------------- LayerNorm -> bf16 ----------------
__global__ __launch_bounds__(256) void ln_kernel(const float* __restrict__ x,
                                                 const float* __restrict__ gamma,
                                                 const float* __restrict__ beta,
                                                 short* __restrict__ xnq) {
  int wave = threadIdx.x >> 6;
  int lane = threadIdx.x & 63;
  int row = blockIdx.x * 4 + wave;
  if (row >= NTOK) return;
  const float* xr = x + (size_t)row * DIMD;
  float v[12];
  float s = 0.f, ss = 0.f;
#pragma unroll
  for (int i = 0; i < 12; ++i) {
    v[i] = xr[lane + i*64];
    s += v[i];
    ss += v[i]*v[i];
  }
#pragma unroll
  for (int m = 1; m < 64; m <<= 1) {
    s  += __shfl_xor(s, m);
    ss += __shfl_xor(ss, m);
  }
  float mu   = s * (1.f/DIMD);
  float var  = ss * (1.f/DIMD) - mu*mu;
  float rstd = rsqrtf(var + EPSV);
  short* o = xnq + (size_t)row * DIMD;
#pragma unroll
  for (int i = 0; i < 12; ++i) {
    int j = lane + i*64;
    o[j] = f2bf((v[i] - mu) * rstd * gamma[j] + beta[j]);
  }
}

// ---------------- weight f32->bf16 (W_x: B/C rows interleaved, pad to 192) ----------------
#define NW_IN  (3072*768)
#define NW_OUT (768*1536)
#define NW_XP  (192*1536)
__global__ __launch_bounds__(256) void cvt_weights_kernel(const float* __restrict__ Win,
                                                          const float* __restrict__ Wout,
                                                          const float* __restrict__ Wx,
                                                          short* __restrict__ qin,
                                                          short* __restrict__ qout,
                                                          short* __restrict__ qx) {
  int idx = blockIdx.x * 256 + threadIdx.x;
  if (idx < NW_IN) { qin[idx] = f2bf(Win[idx]); return; }
  idx -= NW_IN;
  if (idx < NW_OUT) { qout[idx] = f2bf(Wout[idx]); return; }
  idx -= NW_OUT;
  if (idx < NW_XP) {
    int r = idx / 1536, col = idx % 1536;
    int srcr;
    if (r < 48) srcr = r;                                   // dt rows
    else if (r < 176) {                                     // interleave B/C
      int n = r - 48;
      srcr = (n & 1) ? 112 + (n >> 1) : 48 + (n >> 1);
    } else srcr = -1;
    qx[idx] = (srcr >= 0) ? f2bf(Wx[(size_t)srcr * 1536 + col]) : (short)0;
  }
}

// ---------------- bf16 MFMA NT GEMM with optional split-K ----------------
template<int BN>
__global__ __launch_bounds__(256) void gemm_mfma(const short* __restrict__ A,
                                                 const short* __restrict__ B,
                                                 float* __restrict__ C, int ldc,
                                                 int Kfull, int Kchunk, size_t partStride) {
  constexpr int BM = 128, BK = 64;
  constexpr int WN = (BN == 128) ? 2 : 1;
  constexpr int WM = 4 / WN;
  constexpr int MFR = BM / (WM * 16);
  constexpr int NFR = BN / (WN * 16);
  constexpr int BSW = (BN * BK * 2) / 4096;
  __shared__ short As[BM * BK];
  __shared__ short Bs[BN * BK];
  const int tid  = threadIdx.x;
  const int wave = tid >> 6, lane = tid & 63;
  const int m0 = blockIdx.y * BM;
  const int n0 = blockIdx.x * BN;
  const int wm = wave / WN, wn = wave % WN;
  const int kBeg = blockIdx.z * Kchunk;
  const int kEnd = kBeg + Kchunk;
  C += (size_t)blockIdx.z * partStride;

  const short* aSrc = A + (size_t)(m0 + (tid >> 3)) * Kfull + (tid & 7) * 8;
  const short* bSrc = B + (size_t)(n0 + (tid >> 3)) * Kfull + (tid & 7) * 8;

  f32x4 acc[MFR][NFR];
#pragma unroll
  for (int i = 0; i < MFR; ++i)
#pragma unroll
    for (int j = 0; j < NFR; ++j)
      acc[i][j] = (f32x4){0.f, 0.f, 0.f, 0.f};

  for (int k0 = kBeg; k0 < kEnd; k0 += BK) {
#pragma unroll
    for (int s = 0; s < 4; ++s)
      __builtin_amdgcn_global_load_lds(
        (const __attribute__((address_space(1))) void*)(aSrc + (size_t)s*32*Kfull + k0),
        (__attribute__((address_space(3))) void*)((char*)As + s*4096 + wave*1024),
        16, 0, 0);
#pragma unroll
    for (int s = 0; s < BSW; ++s)
      __builtin_amdgcn_global_load_lds(
        (const __attribute__((address_space(1))) void*)(bSrc + (size_t)s*32*Kfull + k0),
        (__attribute__((address_space(3))) void*)((char*)Bs + s*4096 + wave*1024),
        16, 0, 0);
    __syncthreads();

#pragma unroll
    for (int kk = 0; kk < 2; ++kk) {
      bf16x8 af[MFR], bfr[NFR];
#pragma unroll
      for (int i = 0; i < MFR; ++i) {
        int r = wm * (BM / WM) + i * 16 + (lane & 15);
        af[i] = *(const bf16x8*)&As[r * BK + kk * 32 + (lane >> 4) * 8];
      }
#pragma unroll
      for (int j = 0; j < NFR; ++j) {
        int r = wn * (BN / WN) + j * 16 + (lane & 15);
        bfr[j] = *(const bf16x8*)&Bs[r * BK + kk * 32 + (lane >> 4) * 8];
      }
#pragma unroll
      for (int i = 0; i < MFR; ++i)
#pragma unroll
        for (int j = 0; j < NFR; ++j)
          acc[i][j] = __builtin_amdgcn_mfma_f32_16x16x32_bf16(af[i], bfr[j], acc[i][j], 0, 0, 0);
    }
    __syncthreads();
  }

  const int cn = lane & 15, cr4 = (lane >> 4) * 4;
#pragma unroll
  for (int i = 0; i < MFR; ++i)
#pragma unroll
    for (int j = 0; j < NFR; ++j)
#pragma unroll
      for (int r = 0; r < 4; ++r) {
        int m = m0 + wm * (BM / WM) + i * 16 + cr4 + r;
        int n = n0 + wn * (BN / WN) + j * 16 + cn;
        C[(size_t)m * ldc + n] = acc[i][j][r];
      }
}

// ---------------- split-K partial reduce: out = p0+p1+p2+p3 (fixed order) ----------------
__global__ __launch_bounds__(256) void reduce4_kernel(const float* __restrict__ p,
                                                      float* __restrict__ outb) {
  const int n4 = NTOK * XDBL_P / 4;
  int i = blockIdx.x * 256 + threadIdx.x;
  if (i >= n4) return;
  const float4* p4 = (const float4*)p;
  float4 a = p4[i];
  float4 b = p4[i + n4];
  float4 c = p4[i + 2*n4];
  float4 d = p4[i + 3*n4];
  float4 r;
  r.x = ((a.x + b.x) + c.x) + d.x;
  r.y = ((a.y + b.y) + c.y) + d.y;
  r.z = ((a.z + b.z) + c.z) + d.z;
  r.w = ((a.w + b.w) + c.w) + d.w;
  ((float4*)outb)[i] = r;
}

// ---------------- fp32 NT GEMM. ACT: 0 none, 2 = bias[m]+softplus (row bias) ----------------
template<int ACT>
__global__ __launch_bounds__(256) void gemm_nt(const float* __restrict__ A, int lda,
                                               const float* __restrict__ W, int ldw,
                                               const float* __restrict__ bias,
                                               float* __restrict__ C, int ldc,
                                               int M, int N, int K) {
  __shared__ float Asl[16][68];
  __shared__ float Wsl[16][68];
  int tid = threadIdx.x;
  int m0 = blockIdx.y * 64;
  int n0 = blockIdx.x * 64;
  int lrow = tid >> 2;
  int lq   = tid & 3;
  int tx = tid & 15;
  int ty = tid >> 4;
  float acc[4][4] = {{0.f}};

  for (int k0 = 0; k0 < K; k0 += 16) {
    float4 av = make_float4(0.f,0.f,0.f,0.f);
    int ar = m0 + lrow;
    if (ar < M) av = *(const float4*)(A + (size_t)ar*lda + k0 + lq*4);
    float4 wv = make_float4(0.f,0.f,0.f,0.f);
    int wr = n0 + lrow;
    if (wr < N) wv = *(const float4*)(W + (size_t)wr*ldw + k0 + lq*4);
    __syncthreads();
    Asl[lq*4+0][lrow] = av.x; Asl[lq*4+1][lrow] = av.y;
    Asl[lq*4+2][lrow] = av.z; Asl[lq*4+3][lrow] = av.w;
    Wsl[lq*4+0][lrow] = wv.x; Wsl[lq*4+1][lrow] = wv.y;
    Wsl[lq*4+2][lrow] = wv.z; Wsl[lq*4+3][lrow] = wv.w;
    __syncthreads();
#pragma unroll
    for (int kk = 0; kk < 16; ++kk) {
      float4 a4 = *(const float4*)&Asl[kk][ty*4];
      float4 w4 = *(const float4*)&Wsl[kk][tx*4];
      float a[4] = {a4.x, a4.y, a4.z, a4.w};
      float w[4] = {w4.x, w4.y, w4.z, w4.w};
#pragma unroll
      for (int i = 0; i < 4; ++i)
#pragma unroll
        for (int j = 0; j < 4; ++j)
          acc[i][j] += a[i]*w[j];
    }
  }

#pragma unroll
  for (int i = 0; i < 4; ++i) {
    int m = m0 + ty*4 + i;
    if (m >= M) continue;
    float* crow = C + (size_t)m*ldc;
    float bm = (ACT == 2) ? bias[m] : 0.f;
#pragma unroll
    for (int j = 0; j < 4; ++j) {
      int n = n0 + tx*4 + j;
      if (n >= N) continue;
      float val = acc[i][j];
      if (ACT == 2) {
        val += bm;
        val = (val > 20.f) ? val : log1pf(__expf(val));
      }
      crow[n] = val;
    }
  }
}

// ---------------- conv(4)+SiLU, sliding-window: ucq[tok][ch] bf16 + uT[ch][tok] f32 ----------------
// Each thread: 16 CONSECUTIVE tokens of one channel; 3 carried regs -> 19 loads/16 outputs.
__global__ __launch_bounds__(256) void conv_silu_kernel(const float* __restrict__ xz,
                                                        const float* __restrict__ conv_w,
                                                        const float* __restrict__ conv_b,
                                                        float* __restrict__ uT,
                                                        short* __restrict__ ucq) {
  __shared__ float tile[64][65];
  int b  = blockIdx.z;
  int c0 = blockIdx.x * 64;
  int t0 = blockIdx.y * 64;
  int lx = threadIdx.x & 63;
  int ly = threadIdx.x >> 6;
  int c = c0 + lx;
  const int S = 2*DINNER;
  float w0 = conv_w[c*4+0], w1 = conv_w[c*4+1], w2 = conv_w[c*4+2], w3 = conv_w[c*4+3];
  float cb = conv_b[c];
  int ts = t0 + ly*16;                       // 16 consecutive tokens
  const float* col = xz + ((size_t)b*SEQL + ts) * S + c;
  float x3 = (ts >= 3) ? col[-3*S] : 0.f;
  float x2 = (ts >= 2) ? col[-2*S] : 0.f;
  float x1 = (ts >= 1) ? col[-1*S] : 0.f;
#pragma unroll
  for (int i = 0; i < 16; ++i) {
    float x0 = col[(size_t)i*S];
    float acc = cb + x3*w0 + x2*w1 + x1*w2 + x0*w3;
    float sig = 1.f / (1.f + __expf(-acc));
    float v = acc * sig;
    ucq[((size_t)b*SEQL + ts + i)*DINNER + c] = f2bf(v);
    tile[lx][ly*16 + i] = v;
    x3 = x2; x2 = x1; x1 = x0;
  }
  __syncthreads();
#pragma unroll
  for (int i = 0; i < 16; ++i) {
    int cl = ly*16 + i;
    uT[((size_t)(c0 + cl))*NTOK + (size_t)b*SEQL + t0 + lx] = tile[cl][lx];
  }
}

__device__ inline float readlane_f(float v, int l) {
  return __int_as_float(__builtin_amdgcn_readlane(__float_as_int(v), l));
}

// ---------------- Selective scan v11 = v10 + paired-BC dwordx2 + raw exp2 ----------------
__global__ __launch_bounds__(256) void scan_kernel(const float* __restrict__ dT,
                                                   const float* __restrict__ x_dbl,
                                                   const float* __restrict__ uT,
                                                   const float* __restrict__ A_log,
                                                   const float* __restrict__ Dp,
                                                   float* __restrict__ yT) {
  __shared__ float red_all[4][32*66 + 32];
  int tid  = threadIdx.x;
  int wave = tid >> 6;
  int lane = tid & 63;
  float* red = red_all[wave];
  int ch = blockIdx.x * 4 + wave;
  int b = ch / DINNER;
  int c = ch % DINNER;
  float Ac2 = -__expf(A_log[(size_t)c*64 + lane]) * 1.44269504f;  // pre-scaled log2e
  float Dc = Dp[c];
  float h = 0.f;
  const float* dp = dT + (size_t)c * NTOK + (size_t)b * SEQL;
  const float* up = uT + (size_t)c * NTOK + (size_t)b * SEQL;
  float* yrow = yT + ((size_t)b*DINNER + c) * SEQL;
  // paired B/C: lane n reads float2 {B_n, C_n} at col 48 + 2n
  const float* xBC = x_dbl + ((size_t)b * SEQL) * XDBL_P + DTRANK + 2*lane;

  float d_v = dp[lane];
  float u_v = up[lane];

  const int r = lane & 31, hs = lane >> 5;
  const int NBLK = SEQL/64;
  for (int tb = 0; tb < NBLK; ++tb) {
    int t0 = tb*64;
    float d_nxt = 0.f, u_nxt = 0.f;
    if (tb + 1 < NBLK) {
      d_nxt = dp[t0 + 64 + lane];
      u_nxt = up[t0 + 64 + lane];
    }
    float du_v = d_v * u_v;

#pragma unroll
    for (int half = 0; half < 2; ++half) {
      const float* xh = xBC + (size_t)(t0 + half*32) * XDBL_P;
#pragma unroll
      for (int k = 0; k < 32; ++k) {
        int i = half*32 + k;
        float2 BC = *(const float2*)&xh[(size_t)k * XDBL_P];  // 1 dwordx2, coalesced
        float sd  = readlane_f(d_v,  i);
        float sdu = readlane_f(du_v, i);
        float dA = __builtin_amdgcn_exp2f(sd * Ac2);          // raw v_exp_f32
        h = fmaf(dA, h, sdu * BC.x);
        red[k*66 + lane] = h * BC.y;
      }
      {                                           // reduce 32 tokens, 2 lanes/row
        const float2* rp2 = (const float2*)&red[r*66 + hs*32];
        float2 a0 = rp2[0], a1 = rp2[1];
#pragma unroll
        for (int jj = 1; jj < 8; ++jj) {
          float2 v0 = rp2[2*jj], v1 = rp2[2*jj + 1];
          a0.x += v0.x; a0.y += v0.y;
          a1.x += v1.x; a1.y += v1.y;
        }
        float y = (a0.x + a0.y) + (a1.x + a1.y);
        y += __shfl_xor(y, 32);
        float ut = __shfl(u_v, half*32 + r);
        y = fmaf(Dc, ut, y);
        if (lane < 32) yrow[t0 + half*32 + lane] = y;
      }
    }
    __syncthreads();   // phase-lock the 4 waves once per 64 tokens (L1 locality)
    d_v = d_nxt;
    u_v = u_nxt;
  }
}

// ---------------- gate: g[b,t,c] = yT[b,c,t] * silu(z[b,t,c]) -> bf16 ----------------
__global__ __launch_bounds__(256) void ymul_kernel(const float* __restrict__ yT,
                                                   const float* __restrict__ xz,
                                                   short* __restrict__ g) {
  __shared__ float tile[64][65];
  int b  = blockIdx.z;
  int c0 = blockIdx.x * 64;
  int t0 = blockIdx.y * 64;
  int lx = threadIdx.x & 63;
  int ly = threadIdx.x >> 6;
  const float* src = yT + ((size_t)b*DINNER + c0) * SEQL + t0;
#pragma unroll
  for (int i = 0; i < 16; ++i) {
    int c = ly*16 + i;
    tile[c][lx] = src[(size_t)c*SEQL + lx];
  }
  __syncthreads();
  const int S = 2*DINNER;
#pragma unroll
  for (int i = 0; i < 16; ++i) {
    int t = ly*16 + i;
    float z = xz[((size_t)b*SEQL + t0 + t)*S + DINNER + c0 + lx];
    float zs = z / (1.f + __expf(-z));
    g[((size_t)b*SEQL + t0 + t)*DINNER + c0 + lx] = f2bf(tile[lx][t] * zs);
  }
}

extern "C" void kernel_launch(void* const* d_in, const int* in_sizes, int n_in,
                              void* d_out, int out_size, void* d_ws, size_t ws_size,
                              hipStream_t stream) {
  const float* x      = (const float*)d_in[0];
  const float* gamma  = (const float*)d_in[1];
  const float* beta   = (const float*)d_in[2];
  const float* W_in   = (const float*)d_in[3];
  const float* conv_w = (const float*)d_in[4];
  const float* conv_b = (const float*)d_in[5];
  const float* W_x    = (const float*)d_in[6];
  const float* W_dt   = (const float*)d_in[7];
  const float* b_dt   = (const float*)d_in[8];
  const float* A_log  = (const float*)d_in[9];
  const float* Dvec   = (const float*)d_in[10];
  const float* W_out  = (const float*)d_in[11];
  float* out = (float*)d_out;

  float* ws = (float*)d_ws;
  float* xz    = ws;                                  // NTOK*3072
  float* uT    = xz    + (size_t)NTOK*3072;           // DINNER*NTOK
  float* xdbl  = uT    + (size_t)NTOK*1536;           // NTOK*192
  float* dltT  = xdbl  + (size_t)NTOK*XDBL_P;         // DINNER*NTOK
  float* yT    = dltT  + (size_t)NTOK*1536;           // NTOK*1536
  float* xpart = yT    + (size_t)NTOK*1536;           // 4 * NTOK*192
  short* xnq   = (short*)(xpart + (size_t)4*NTOK*XDBL_P);
  short* ucq   = xnq  + (size_t)NTOK*768;
  short* gq    = ucq  + (size_t)NTOK*1536;
  short* qin   = gq   + (size_t)NTOK*1536;
  short* qx    = qin  + (size_t)NW_IN;
  short* qout  = qx   + (size_t)NW_XP;

  cvt_weights_kernel<<<(NW_IN+NW_OUT+NW_XP+255)/256, 256, 0, stream>>>(W_in, W_out, W_x, qin, qout, qx);
  ln_kernel<<<NTOK/4, 256, 0, stream>>>(x, gamma, beta, xnq);
  gemm_mfma<64><<<dim3(3072/64, NTOK/128), 256, 0, stream>>>(xnq, qin, xz, 3072, DIMD, DIMD, 0);
  conv_silu_kernel<<<dim3(DINNER/64, SEQL/64, BATCH), 256, 0, stream>>>(xz, conv_w, conv_b, uT, ucq);
  gemm_mfma<64><<<dim3(XDBL_P/64, NTOK/128, 4), 256, 0, stream>>>(ucq, qx, xpart, XDBL_P,
                                                                  DINNER, DINNER/4,
                                                                  (size_t)NTOK*XDBL_P);
  reduce4_kernel<<<(NTOK*XDBL_P/4 + 255)/256, 256, 0, stream>>>(xpart, xdbl);
  gemm_nt<2><<<dim3(NTOK/64, DINNER/64), 256, 0, stream>>>(W_dt, DTRANK, xdbl, XDBL_P, b_dt,
                                                           dltT, NTOK, DINNER, NTOK, DTRANK);
  scan_kernel<<<BATCH*DINNER/4, 256, 0, stream>>>(dltT, xdbl, uT, A_log, Dvec, yT);
  ymul_kernel<<<dim3(DINNER/64, SEQL/64, BATCH), 256, 0, stream>>>(yT, xz, gq);
  gemm_mfma<64><<<dim3(DIMD/64, NTOK/128), 256, 0, stream>>>(gq, qout, out, DIMD, DINNER, DINNER, 0);
}

// Round 13
// 184.520 us; speedup vs baseline: 1.1246x; 1.1246x over previous
//
#include <hip/hip_runtime.h>
#include <math.h>

#define DIMD 768
#define DSTATE 64
#define DINNER 1536
#define DTRANK 48
#define BATCH 2
#define SEQL 1024
#define NTOK (BATCH*SEQL)
#define XDBL_P 192              // padded x_dbl row stride (176 -> 192)
#define EPSV 1e-5f

typedef __attribute__((ext_vector_type(8))) short bf16x8;
typedef __attribute__((ext_vector_type(4))) float f32x4;

__device__ inline short f2bf(float f) {             // RTNE f32 -> bf16
  unsigned u = __float_as_uint(f);
  u = u + 0x7FFFu + ((u >> 16) & 1u);
  return (short)(u >> 16);
}

// ---------------- LayerNorm -> bf16 ----------------
__global__ __launch_bounds__(256) void ln_kernel(const float* __restrict__ x,
                                                 const float* __restrict__ gamma,
                                                 const float* __restrict__ beta,
                                                 short* __restrict__ xnq) {
  int wave = threadIdx.x >> 6;
  int lane = threadIdx.x & 63;
  int row = blockIdx.x * 4 + wave;
  if (row >= NTOK) return;
  const float* xr = x + (size_t)row * DIMD;
  float v[12];
  float s = 0.f, ss = 0.f;
#pragma unroll
  for (int i = 0; i < 12; ++i) {
    v[i] = xr[lane + i*64];
    s += v[i];
    ss += v[i]*v[i];
  }
#pragma unroll
  for (int m = 1; m < 64; m <<= 1) {
    s  += __shfl_xor(s, m);
    ss += __shfl_xor(ss, m);
  }
  float mu   = s * (1.f/DIMD);
  float var  = ss * (1.f/DIMD) - mu*mu;
  float rstd = rsqrtf(var + EPSV);
  short* o = xnq + (size_t)row * DIMD;
#pragma unroll
  for (int i = 0; i < 12; ++i) {
    int j = lane + i*64;
    o[j] = f2bf((v[i] - mu) * rstd * gamma[j] + beta[j]);
  }
}

// ---------------- weight f32->bf16 (W_x padded 176->192 rows) ----------------
#define NW_IN  (3072*768)
#define NW_OUT (768*1536)
#define NW_XP  (192*1536)
__global__ __launch_bounds__(256) void cvt_weights_kernel(const float* __restrict__ Win,
                                                          const float* __restrict__ Wout,
                                                          const float* __restrict__ Wx,
                                                          short* __restrict__ qin,
                                                          short* __restrict__ qout,
                                                          short* __restrict__ qx) {
  int idx = blockIdx.x * 256 + threadIdx.x;
  if (idx < NW_IN) { qin[idx] = f2bf(Win[idx]); return; }
  idx -= NW_IN;
  if (idx < NW_OUT) { qout[idx] = f2bf(Wout[idx]); return; }
  idx -= NW_OUT;
  if (idx < NW_XP) {
    int r = idx / 1536;
    qx[idx] = (r < 176) ? f2bf(Wx[idx]) : (short)0;
  }
}

// ---------------- bf16 MFMA NT GEMM with optional split-K ----------------
template<int BN>
__global__ __launch_bounds__(256) void gemm_mfma(const short* __restrict__ A,
                                                 const short* __restrict__ B,
                                                 float* __restrict__ C, int ldc,
                                                 int Kfull, int Kchunk, size_t partStride) {
  constexpr int BM = 128, BK = 64;
  constexpr int WN = (BN == 128) ? 2 : 1;
  constexpr int WM = 4 / WN;
  constexpr int MFR = BM / (WM * 16);
  constexpr int NFR = BN / (WN * 16);
  constexpr int BSW = (BN * BK * 2) / 4096;
  __shared__ short As[BM * BK];
  __shared__ short Bs[BN * BK];
  const int tid  = threadIdx.x;
  const int wave = tid >> 6, lane = tid & 63;
  const int m0 = blockIdx.y * BM;
  const int n0 = blockIdx.x * BN;
  const int wm = wave / WN, wn = wave % WN;
  const int kBeg = blockIdx.z * Kchunk;
  const int kEnd = kBeg + Kchunk;
  C += (size_t)blockIdx.z * partStride;

  const short* aSrc = A + (size_t)(m0 + (tid >> 3)) * Kfull + (tid & 7) * 8;
  const short* bSrc = B + (size_t)(n0 + (tid >> 3)) * Kfull + (tid & 7) * 8;

  f32x4 acc[MFR][NFR];
#pragma unroll
  for (int i = 0; i < MFR; ++i)
#pragma unroll
    for (int j = 0; j < NFR; ++j)
      acc[i][j] = (f32x4){0.f, 0.f, 0.f, 0.f};

  for (int k0 = kBeg; k0 < kEnd; k0 += BK) {
#pragma unroll
    for (int s = 0; s < 4; ++s)
      __builtin_amdgcn_global_load_lds(
        (const __attribute__((address_space(1))) void*)(aSrc + (size_t)s*32*Kfull + k0),
        (__attribute__((address_space(3))) void*)((char*)As + s*4096 + wave*1024),
        16, 0, 0);
#pragma unroll
    for (int s = 0; s < BSW; ++s)
      __builtin_amdgcn_global_load_lds(
        (const __attribute__((address_space(1))) void*)(bSrc + (size_t)s*32*Kfull + k0),
        (__attribute__((address_space(3))) void*)((char*)Bs + s*4096 + wave*1024),
        16, 0, 0);
    __syncthreads();

#pragma unroll
    for (int kk = 0; kk < 2; ++kk) {
      bf16x8 af[MFR], bfr[NFR];
#pragma unroll
      for (int i = 0; i < MFR; ++i) {
        int r = wm * (BM / WM) + i * 16 + (lane & 15);
        af[i] = *(const bf16x8*)&As[r * BK + kk * 32 + (lane >> 4) * 8];
      }
#pragma unroll
      for (int j = 0; j < NFR; ++j) {
        int r = wn * (BN / WN) + j * 16 + (lane & 15);
        bfr[j] = *(const bf16x8*)&Bs[r * BK + kk * 32 + (lane >> 4) * 8];
      }
#pragma unroll
      for (int i = 0; i < MFR; ++i)
#pragma unroll
        for (int j = 0; j < NFR; ++j)
          acc[i][j] = __builtin_amdgcn_mfma_f32_16x16x32_bf16(af[i], bfr[j], acc[i][j], 0, 0, 0);
    }
    __syncthreads();
  }

  const int cn = lane & 15, cr4 = (lane >> 4) * 4;
#pragma unroll
  for (int i = 0; i < MFR; ++i)
#pragma unroll
    for (int j = 0; j < NFR; ++j)
#pragma unroll
      for (int r = 0; r < 4; ++r) {
        int m = m0 + wm * (BM / WM) + i * 16 + cr4 + r;
        int n = n0 + wn * (BN / WN) + j * 16 + cn;
        C[(size_t)m * ldc + n] = acc[i][j][r];
      }
}

// ---------------- split-K partial reduce: out = p0+p1+p2+p3 (fixed order) ----------------
__global__ __launch_bounds__(256) void reduce4_kernel(const float* __restrict__ p,
                                                      float* __restrict__ outb) {
  const int n4 = NTOK * XDBL_P / 4;
  int i = blockIdx.x * 256 + threadIdx.x;
  if (i >= n4) return;
  const float4* p4 = (const float4*)p;
  float4 a = p4[i];
  float4 b = p4[i + n4];
  float4 c = p4[i + 2*n4];
  float4 d = p4[i + 3*n4];
  float4 r;
  r.x = ((a.x + b.x) + c.x) + d.x;
  r.y = ((a.y + b.y) + c.y) + d.y;
  r.z = ((a.z + b.z) + c.z) + d.z;
  r.w = ((a.w + b.w) + c.w) + d.w;
  ((float4*)outb)[i] = r;
}

// ---------------- fp32 NT GEMM. ACT: 0 none, 2 = bias[m]+softplus (row bias) ----------------
template<int ACT>
__global__ __launch_bounds__(256) void gemm_nt(const float* __restrict__ A, int lda,
                                               const float* __restrict__ W, int ldw,
                                               const float* __restrict__ bias,
                                               float* __restrict__ C, int ldc,
                                               int M, int N, int K) {
  __shared__ float Asl[16][68];
  __shared__ float Wsl[16][68];
  int tid = threadIdx.x;
  int m0 = blockIdx.y * 64;
  int n0 = blockIdx.x * 64;
  int lrow = tid >> 2;
  int lq   = tid & 3;
  int tx = tid & 15;
  int ty = tid >> 4;
  float acc[4][4] = {{0.f}};

  for (int k0 = 0; k0 < K; k0 += 16) {
    float4 av = make_float4(0.f,0.f,0.f,0.f);
    int ar = m0 + lrow;
    if (ar < M) av = *(const float4*)(A + (size_t)ar*lda + k0 + lq*4);
    float4 wv = make_float4(0.f,0.f,0.f,0.f);
    int wr = n0 + lrow;
    if (wr < N) wv = *(const float4*)(W + (size_t)wr*ldw + k0 + lq*4);
    __syncthreads();
    Asl[lq*4+0][lrow] = av.x; Asl[lq*4+1][lrow] = av.y;
    Asl[lq*4+2][lrow] = av.z; Asl[lq*4+3][lrow] = av.w;
    Wsl[lq*4+0][lrow] = wv.x; Wsl[lq*4+1][lrow] = wv.y;
    Wsl[lq*4+2][lrow] = wv.z; Wsl[lq*4+3][lrow] = wv.w;
    __syncthreads();
#pragma unroll
    for (int kk = 0; kk < 16; ++kk) {
      float4 a4 = *(const float4*)&Asl[kk][ty*4];
      float4 w4 = *(const float4*)&Wsl[kk][tx*4];
      float a[4] = {a4.x, a4.y, a4.z, a4.w};
      float w[4] = {w4.x, w4.y, w4.z, w4.w};
#pragma unroll
      for (int i = 0; i < 4; ++i)
#pragma unroll
        for (int j = 0; j < 4; ++j)
          acc[i][j] += a[i]*w[j];
    }
  }

#pragma unroll
  for (int i = 0; i < 4; ++i) {
    int m = m0 + ty*4 + i;
    if (m >= M) continue;
    float* crow = C + (size_t)m*ldc;
    float bm = (ACT == 2) ? bias[m] : 0.f;
#pragma unroll
    for (int j = 0; j < 4; ++j) {
      int n = n0 + tx*4 + j;
      if (n >= N) continue;
      float val = acc[i][j];
      if (ACT == 2) {
        val += bm;
        val = (val > 20.f) ? val : log1pf(__expf(val));
      }
      crow[n] = val;
    }
  }
}

// ---------------- conv(4)+SiLU, sliding-window: ucq[tok][ch] bf16 + uT[ch][tok] f32 ----------------
__global__ __launch_bounds__(256) void conv_silu_kernel(const float* __restrict__ xz,
                                                        const float* __restrict__ conv_w,
                                                        const float* __restrict__ conv_b,
                                                        float* __restrict__ uT,
                                                        short* __restrict__ ucq) {
  __shared__ float tile[64][65];
  int b  = blockIdx.z;
  int c0 = blockIdx.x * 64;
  int t0 = blockIdx.y * 64;
  int lx = threadIdx.x & 63;
  int ly = threadIdx.x >> 6;
  int c = c0 + lx;
  const int S = 2*DINNER;
  float w0 = conv_w[c*4+0], w1 = conv_w[c*4+1], w2 = conv_w[c*4+2], w3 = conv_w[c*4+3];
  float cb = conv_b[c];
  int ts = t0 + ly*16;                       // 16 consecutive tokens
  const float* col = xz + ((size_t)b*SEQL + ts) * S + c;
  float x3 = (ts >= 3) ? col[-3*S] : 0.f;
  float x2 = (ts >= 2) ? col[-2*S] : 0.f;
  float x1 = (ts >= 1) ? col[-1*S] : 0.f;
#pragma unroll
  for (int i = 0; i < 16; ++i) {
    float x0 = col[(size_t)i*S];
    float acc = cb + x3*w0 + x2*w1 + x1*w2 + x0*w3;
    float sig = 1.f / (1.f + __expf(-acc));
    float v = acc * sig;
    ucq[((size_t)b*SEQL + ts + i)*DINNER + c] = f2bf(v);
    tile[lx][ly*16 + i] = v;
    x3 = x2; x2 = x1; x1 = x0;
  }
  __syncthreads();
#pragma unroll
  for (int i = 0; i < 16; ++i) {
    int cl = ly*16 + i;
    uT[((size_t)(c0 + cl))*NTOK + (size_t)b*SEQL + t0 + lx] = tile[cl][lx];
  }
}

__device__ inline float readlane_f(float v, int l) {
  return __int_as_float(__builtin_amdgcn_readlane(__float_as_int(v), l));
}

// ---------------- Selective scan v12 = v10 structure + pre-scaled exp2 only ----------------
// Separate coalesced B/C dword loads (paired dwordx2 regressed: 3-line span).
__global__ __launch_bounds__(256) void scan_kernel(const float* __restrict__ dT,
                                                   const float* __restrict__ x_dbl,
                                                   const float* __restrict__ uT,
                                                   const float* __restrict__ A_log,
                                                   const float* __restrict__ Dp,
                                                   float* __restrict__ yT) {
  __shared__ float red_all[4][32*66 + 32];
  int tid  = threadIdx.x;
  int wave = tid >> 6;
  int lane = tid & 63;
  float* red = red_all[wave];
  int ch = blockIdx.x * 4 + wave;
  int b = ch / DINNER;
  int c = ch % DINNER;
  float Ac2 = -__expf(A_log[(size_t)c*64 + lane]) * 1.44269504f;  // pre-scaled log2e
  float Dc = Dp[c];
  float h = 0.f;
  const float* dp = dT + (size_t)c * NTOK + (size_t)b * SEQL;
  const float* up = uT + (size_t)c * NTOK + (size_t)b * SEQL;
  float* yrow = yT + ((size_t)b*DINNER + c) * SEQL;
  const float* xB = x_dbl + ((size_t)b * SEQL) * XDBL_P + DTRANK + lane;  // per-lane B ptr

  float d_v = dp[lane];
  float u_v = up[lane];

  const int r = lane & 31, hs = lane >> 5;
  const int NBLK = SEQL/64;
  for (int tb = 0; tb < NBLK; ++tb) {
    int t0 = tb*64;
    float d_nxt = 0.f, u_nxt = 0.f;
    if (tb + 1 < NBLK) {
      d_nxt = dp[t0 + 64 + lane];
      u_nxt = up[t0 + 64 + lane];
    }
    float du_v = d_v * u_v;

#pragma unroll
    for (int half = 0; half < 2; ++half) {
      const float* xh = xB + (size_t)(t0 + half*32) * XDBL_P;
#pragma unroll
      for (int k = 0; k < 32; ++k) {
        int i = half*32 + k;
        float Bv = xh[(size_t)k * XDBL_P];        // global b32, coalesced, L1/L2-hot
        float Cv = xh[(size_t)k * XDBL_P + DSTATE];
        float sd  = readlane_f(d_v,  i);
        float sdu = readlane_f(du_v, i);
        float dA = __builtin_amdgcn_exp2f(sd * Ac2);   // raw v_exp_f32 (1 mul saved)
        h = fmaf(dA, h, sdu * Bv);
        red[k*66 + lane] = h * Cv;
      }
      {                                           // reduce 32 tokens, 2 lanes/row
        const float2* rp2 = (const float2*)&red[r*66 + hs*32];
        float2 a0 = rp2[0], a1 = rp2[1];
#pragma unroll
        for (int jj = 1; jj < 8; ++jj) {
          float2 v0 = rp2[2*jj], v1 = rp2[2*jj + 1];
          a0.x += v0.x; a0.y += v0.y;
          a1.x += v1.x; a1.y += v1.y;
        }
        float y = (a0.x + a0.y) + (a1.x + a1.y);
        y += __shfl_xor(y, 32);
        float ut = __shfl(u_v, half*32 + r);
        y = fmaf(Dc, ut, y);
        if (lane < 32) yrow[t0 + half*32 + lane] = y;
      }
    }
    __syncthreads();   // phase-lock the 4 waves once per 64 tokens (L1 locality)
    d_v = d_nxt;
    u_v = u_nxt;
  }
}

// ---------------- gate: g[b,t,c] = yT[b,c,t] * silu(z[b,t,c]) -> bf16 ----------------
__global__ __launch_bounds__(256) void ymul_kernel(const float* __restrict__ yT,
                                                   const float* __restrict__ xz,
                                                   short* __restrict__ g) {
  __shared__ float tile[64][65];
  int b  = blockIdx.z;
  int c0 = blockIdx.x * 64;
  int t0 = blockIdx.y * 64;
  int lx = threadIdx.x & 63;
  int ly = threadIdx.x >> 6;
  const float* src = yT + ((size_t)b*DINNER + c0) * SEQL + t0;
#pragma unroll
  for (int i = 0; i < 16; ++i) {
    int c = ly*16 + i;
    tile[c][lx] = src[(size_t)c*SEQL + lx];
  }
  __syncthreads();
  const int S = 2*DINNER;
#pragma unroll
  for (int i = 0; i < 16; ++i) {
    int t = ly*16 + i;
    float z = xz[((size_t)b*SEQL + t0 + t)*S + DINNER + c0 + lx];
    float zs = z / (1.f + __expf(-z));
    g[((size_t)b*SEQL + t0 + t)*DINNER + c0 + lx] = f2bf(tile[lx][t] * zs);
  }
}

extern "C" void kernel_launch(void* const* d_in, const int* in_sizes, int n_in,
                              void* d_out, int out_size, void* d_ws, size_t ws_size,
                              hipStream_t stream) {
  const float* x      = (const float*)d_in[0];
  const float* gamma  = (const float*)d_in[1];
  const float* beta   = (const float*)d_in[2];
  const float* W_in   = (const float*)d_in[3];
  const float* conv_w = (const float*)d_in[4];
  const float* conv_b = (const float*)d_in[5];
  const float* W_x    = (const float*)d_in[6];
  const float* W_dt   = (const float*)d_in[7];
  const float* b_dt   = (const float*)d_in[8];
  const float* A_log  = (const float*)d_in[9];
  const float* Dvec   = (const float*)d_in[10];
  const float* W_out  = (const float*)d_in[11];
  float* out = (float*)d_out;

  float* ws = (float*)d_ws;
  float* xz    = ws;                                  // NTOK*3072
  float* uT    = xz    + (size_t)NTOK*3072;           // DINNER*NTOK
  float* xdbl  = uT    + (size_t)NTOK*1536;           // NTOK*192
  float* dltT  = xdbl  + (size_t)NTOK*XDBL_P;         // DINNER*NTOK
  float* yT    = dltT  + (size_t)NTOK*1536;           // NTOK*1536
  float* xpart = yT    + (size_t)NTOK*1536;           // 4 * NTOK*192
  short* xnq   = (short*)(xpart + (size_t)4*NTOK*XDBL_P);
  short* ucq   = xnq  + (size_t)NTOK*768;
  short* gq    = ucq  + (size_t)NTOK*1536;
  short* qin   = gq   + (size_t)NTOK*1536;
  short* qx    = qin  + (size_t)NW_IN;
  short* qout  = qx   + (size_t)NW_XP;

  cvt_weights_kernel<<<(NW_IN+NW_OUT+NW_XP+255)/256, 256, 0, stream>>>(W_in, W_out, W_x, qin, qout, qx);
  ln_kernel<<<NTOK/4, 256, 0, stream>>>(x, gamma, beta, xnq);
  gemm_mfma<64><<<dim3(3072/64, NTOK/128), 256, 0, stream>>>(xnq, qin, xz, 3072, DIMD, DIMD, 0);
  conv_silu_kernel<<<dim3(DINNER/64, SEQL/64, BATCH), 256, 0, stream>>>(xz, conv_w, conv_b, uT, ucq);
  gemm_mfma<64><<<dim3(XDBL_P/64, NTOK/128, 4), 256, 0, stream>>>(ucq, qx, xpart, XDBL_P,
                                                                  DINNER, DINNER/4,
                                                                  (size_t)NTOK*XDBL_P);
  reduce4_kernel<<<(NTOK*XDBL_P/4 + 255)/256, 256, 0, stream>>>(xpart, xdbl);
  gemm_nt<2><<<dim3(NTOK/64, DINNER/64), 256, 0, stream>>>(W_dt, DTRANK, xdbl, XDBL_P, b_dt,
                                                           dltT, NTOK, DINNER, NTOK, DTRANK);
  scan_kernel<<<BATCH*DINNER/4, 256, 0, stream>>>(dltT, xdbl, uT, A_log, Dvec, yT);
  ymul_kernel<<<dim3(DINNER/64, SEQL/64, BATCH), 256, 0, stream>>>(yT, xz, gq);
  gemm_mfma<64><<<dim3(DIMD/64, NTOK/128), 256, 0, stream>>>(gq, qout, out, DIMD, DINNER, DINNER, 0);
}

// Round 14
// 180.566 us; speedup vs baseline: 1.1493x; 1.0219x over previous
//
#include <hip/hip_runtime.h>
#include <math.h>

#define DIMD 768
#define DSTATE 64
#define DINNER 1536
#define DTRANK 48
#define BATCH 2
#define SEQL 1024
#define NTOK (BATCH*SEQL)
#define XDBL_P 192              // padded x_dbl row stride (176 -> 192)
#define EPSV 1e-5f

typedef __attribute__((ext_vector_type(8))) short bf16x8;
typedef __attribute__((ext_vector_type(4))) float f32x4;

__device__ inline short f2bf(float f) {             // RTNE f32 -> bf16
  unsigned u = __float_as_uint(f);
  u = u + 0x7FFFu + ((u >> 16) & 1u);
  return (short)(u >> 16);
}
__device__ inline float bf2f(short s) {
  return __uint_as_float(((unsigned)(unsigned short)s) << 16);
}

// ---------------- prep: LayerNorm->bf16 (blocks 0..511) + weight cvt (rest) ----------------
#define NW_IN  (3072*768)
#define NW_OUT (768*1536)
#define NW_XP  (192*1536)
#define LN_BLOCKS (NTOK/4)
__global__ __launch_bounds__(256) void prep_kernel(const float* __restrict__ x,
                                                   const float* __restrict__ gamma,
                                                   const float* __restrict__ beta,
                                                   short* __restrict__ xnq,
                                                   const float* __restrict__ Win,
                                                   const float* __restrict__ Wout,
                                                   const float* __restrict__ Wx,
                                                   short* __restrict__ qin,
                                                   short* __restrict__ qout,
                                                   short* __restrict__ qx) {
  if (blockIdx.x < LN_BLOCKS) {
    int wave = threadIdx.x >> 6;
    int lane = threadIdx.x & 63;
    int row = blockIdx.x * 4 + wave;
    const float* xr = x + (size_t)row * DIMD;
    float v[12];
    float s = 0.f, ss = 0.f;
#pragma unroll
    for (int i = 0; i < 12; ++i) {
      v[i] = xr[lane + i*64];
      s += v[i];
      ss += v[i]*v[i];
    }
#pragma unroll
    for (int m = 1; m < 64; m <<= 1) {
      s  += __shfl_xor(s, m);
      ss += __shfl_xor(ss, m);
    }
    float mu   = s * (1.f/DIMD);
    float var  = ss * (1.f/DIMD) - mu*mu;
    float rstd = rsqrtf(var + EPSV);
    short* o = xnq + (size_t)row * DIMD;
#pragma unroll
    for (int i = 0; i < 12; ++i) {
      int j = lane + i*64;
      o[j] = f2bf((v[i] - mu) * rstd * gamma[j] + beta[j]);
    }
    return;
  }
  int idx = (blockIdx.x - LN_BLOCKS) * 256 + threadIdx.x;
  if (idx < NW_IN) { qin[idx] = f2bf(Win[idx]); return; }
  idx -= NW_IN;
  if (idx < NW_OUT) { qout[idx] = f2bf(Wout[idx]); return; }
  idx -= NW_OUT;
  if (idx < NW_XP) {
    int r = idx / 1536;
    qx[idx] = (r < 176) ? f2bf(Wx[idx]) : (short)0;
  }
}

// ---------------- bf16 MFMA NT GEMM, optional split-K, optional bf16 C ----------------
template<int BN, bool BF16OUT>
__global__ __launch_bounds__(256) void gemm_mfma(const short* __restrict__ A,
                                                 const short* __restrict__ B,
                                                 float* __restrict__ C, int ldc,
                                                 int Kfull, int Kchunk, size_t partStride) {
  constexpr int BM = 128, BK = 64;
  constexpr int WN = (BN == 128) ? 2 : 1;
  constexpr int WM = 4 / WN;
  constexpr int MFR = BM / (WM * 16);
  constexpr int NFR = BN / (WN * 16);
  constexpr int BSW = (BN * BK * 2) / 4096;
  __shared__ short As[BM * BK];
  __shared__ short Bs[BN * BK];
  const int tid  = threadIdx.x;
  const int wave = tid >> 6, lane = tid & 63;
  const int m0 = blockIdx.y * BM;
  const int n0 = blockIdx.x * BN;
  const int wm = wave / WN, wn = wave % WN;
  const int kBeg = blockIdx.z * Kchunk;
  const int kEnd = kBeg + Kchunk;
  C += (size_t)blockIdx.z * partStride;

  const short* aSrc = A + (size_t)(m0 + (tid >> 3)) * Kfull + (tid & 7) * 8;
  const short* bSrc = B + (size_t)(n0 + (tid >> 3)) * Kfull + (tid & 7) * 8;

  f32x4 acc[MFR][NFR];
#pragma unroll
  for (int i = 0; i < MFR; ++i)
#pragma unroll
    for (int j = 0; j < NFR; ++j)
      acc[i][j] = (f32x4){0.f, 0.f, 0.f, 0.f};

  for (int k0 = kBeg; k0 < kEnd; k0 += BK) {
#pragma unroll
    for (int s = 0; s < 4; ++s)
      __builtin_amdgcn_global_load_lds(
        (const __attribute__((address_space(1))) void*)(aSrc + (size_t)s*32*Kfull + k0),
        (__attribute__((address_space(3))) void*)((char*)As + s*4096 + wave*1024),
        16, 0, 0);
#pragma unroll
    for (int s = 0; s < BSW; ++s)
      __builtin_amdgcn_global_load_lds(
        (const __attribute__((address_space(1))) void*)(bSrc + (size_t)s*32*Kfull + k0),
        (__attribute__((address_space(3))) void*)((char*)Bs + s*4096 + wave*1024),
        16, 0, 0);
    __syncthreads();

#pragma unroll
    for (int kk = 0; kk < 2; ++kk) {
      bf16x8 af[MFR], bfr[NFR];
#pragma unroll
      for (int i = 0; i < MFR; ++i) {
        int r = wm * (BM / WM) + i * 16 + (lane & 15);
        af[i] = *(const bf16x8*)&As[r * BK + kk * 32 + (lane >> 4) * 8];
      }
#pragma unroll
      for (int j = 0; j < NFR; ++j) {
        int r = wn * (BN / WN) + j * 16 + (lane & 15);
        bfr[j] = *(const bf16x8*)&Bs[r * BK + kk * 32 + (lane >> 4) * 8];
      }
#pragma unroll
      for (int i = 0; i < MFR; ++i)
#pragma unroll
        for (int j = 0; j < NFR; ++j)
          acc[i][j] = __builtin_amdgcn_mfma_f32_16x16x32_bf16(af[i], bfr[j], acc[i][j], 0, 0, 0);
    }
    __syncthreads();
  }

  const int cn = lane & 15, cr4 = (lane >> 4) * 4;
#pragma unroll
  for (int i = 0; i < MFR; ++i)
#pragma unroll
    for (int j = 0; j < NFR; ++j)
#pragma unroll
      for (int r = 0; r < 4; ++r) {
        int m = m0 + wm * (BM / WM) + i * 16 + cr4 + r;
        int n = n0 + wn * (BN / WN) + j * 16 + cn;
        if constexpr (BF16OUT)
          ((short*)C)[(size_t)m * ldc + n] = f2bf(acc[i][j][r]);
        else
          C[(size_t)m * ldc + n] = acc[i][j][r];
      }
}

// ---------------- split-K partial reduce: out = p0+p1+p2+p3 (fixed order) ----------------
__global__ __launch_bounds__(256) void reduce4_kernel(const float* __restrict__ p,
                                                      float* __restrict__ outb) {
  const int n4 = NTOK * XDBL_P / 4;
  int i = blockIdx.x * 256 + threadIdx.x;
  if (i >= n4) return;
  const float4* p4 = (const float4*)p;
  float4 a = p4[i];
  float4 b = p4[i + n4];
  float4 c = p4[i + 2*n4];
  float4 d = p4[i + 3*n4];
  float4 r;
  r.x = ((a.x + b.x) + c.x) + d.x;
  r.y = ((a.y + b.y) + c.y) + d.y;
  r.z = ((a.z + b.z) + c.z) + d.z;
  r.w = ((a.w + b.w) + c.w) + d.w;
  ((float4*)outb)[i] = r;
}

// ---------------- fp32 NT GEMM. ACT: 0 none, 2 = bias[m]+softplus (row bias) ----------------
template<int ACT>
__global__ __launch_bounds__(256) void gemm_nt(const float* __restrict__ A, int lda,
                                               const float* __restrict__ W, int ldw,
                                               const float* __restrict__ bias,
                                               float* __restrict__ C, int ldc,
                                               int M, int N, int K) {
  __shared__ float Asl[16][68];
  __shared__ float Wsl[16][68];
  int tid = threadIdx.x;
  int m0 = blockIdx.y * 64;
  int n0 = blockIdx.x * 64;
  int lrow = tid >> 2;
  int lq   = tid & 3;
  int tx = tid & 15;
  int ty = tid >> 4;
  float acc[4][4] = {{0.f}};

  for (int k0 = 0; k0 < K; k0 += 16) {
    float4 av = make_float4(0.f,0.f,0.f,0.f);
    int ar = m0 + lrow;
    if (ar < M) av = *(const float4*)(A + (size_t)ar*lda + k0 + lq*4);
    float4 wv = make_float4(0.f,0.f,0.f,0.f);
    int wr = n0 + lrow;
    if (wr < N) wv = *(const float4*)(W + (size_t)wr*ldw + k0 + lq*4);
    __syncthreads();
    Asl[lq*4+0][lrow] = av.x; Asl[lq*4+1][lrow] = av.y;
    Asl[lq*4+2][lrow] = av.z; Asl[lq*4+3][lrow] = av.w;
    Wsl[lq*4+0][lrow] = wv.x; Wsl[lq*4+1][lrow] = wv.y;
    Wsl[lq*4+2][lrow] = wv.z; Wsl[lq*4+3][lrow] = wv.w;
    __syncthreads();
#pragma unroll
    for (int kk = 0; kk < 16; ++kk) {
      float4 a4 = *(const float4*)&Asl[kk][ty*4];
      float4 w4 = *(const float4*)&Wsl[kk][tx*4];
      float a[4] = {a4.x, a4.y, a4.z, a4.w};
      float w[4] = {w4.x, w4.y, w4.z, w4.w};
#pragma unroll
      for (int i = 0; i < 4; ++i)
#pragma unroll
        for (int j = 0; j < 4; ++j)
          acc[i][j] += a[i]*w[j];
    }
  }

#pragma unroll
  for (int i = 0; i < 4; ++i) {
    int m = m0 + ty*4 + i;
    if (m >= M) continue;
    float* crow = C + (size_t)m*ldc;
    float bm = (ACT == 2) ? bias[m] : 0.f;
#pragma unroll
    for (int j = 0; j < 4; ++j) {
      int n = n0 + tx*4 + j;
      if (n >= N) continue;
      float val = acc[i][j];
      if (ACT == 2) {
        val += bm;
        val = (val > 20.f) ? val : log1pf(__expf(val));
      }
      crow[n] = val;
    }
  }
}

// ---------------- conv(4)+SiLU, sliding-window, bf16 input ----------------
__global__ __launch_bounds__(256) void conv_silu_kernel(const short* __restrict__ xzq,
                                                        const float* __restrict__ conv_w,
                                                        const float* __restrict__ conv_b,
                                                        float* __restrict__ uT,
                                                        short* __restrict__ ucq) {
  __shared__ float tile[64][65];
  int b  = blockIdx.z;
  int c0 = blockIdx.x * 64;
  int t0 = blockIdx.y * 64;
  int lx = threadIdx.x & 63;
  int ly = threadIdx.x >> 6;
  int c = c0 + lx;
  const int S = 2*DINNER;
  float w0 = conv_w[c*4+0], w1 = conv_w[c*4+1], w2 = conv_w[c*4+2], w3 = conv_w[c*4+3];
  float cb = conv_b[c];
  int ts = t0 + ly*16;
  const short* col = xzq + ((size_t)b*SEQL + ts) * S + c;
  float x3 = (ts >= 3) ? bf2f(col[-3*S]) : 0.f;
  float x2 = (ts >= 2) ? bf2f(col[-2*S]) : 0.f;
  float x1 = (ts >= 1) ? bf2f(col[-1*S]) : 0.f;
#pragma unroll
  for (int i = 0; i < 16; ++i) {
    float x0 = bf2f(col[(size_t)i*S]);
    float acc = cb + x3*w0 + x2*w1 + x1*w2 + x0*w3;
    float sig = 1.f / (1.f + __expf(-acc));
    float v = acc * sig;
    ucq[((size_t)b*SEQL + ts + i)*DINNER + c] = f2bf(v);
    tile[lx][ly*16 + i] = v;
    x3 = x2; x2 = x1; x1 = x0;
  }
  __syncthreads();
#pragma unroll
  for (int i = 0; i < 16; ++i) {
    int cl = ly*16 + i;
    uT[((size_t)(c0 + cl))*NTOK + (size_t)b*SEQL + t0 + lx] = tile[cl][lx];
  }
}

__device__ inline float readlane_f(float v, int l) {
  return __int_as_float(__builtin_amdgcn_readlane(__float_as_int(v), l));
}

// ---------------- Selective scan v13 = v12 + uniform-base 32-bit addressing ----------------
// b derived from blockIdx only (uniform -> SGPR base); B/C loads share one
// 32-bit voffset with imm 0 / +256. Address VALU per token: ~1 add.
#define CPB (DINNER/4)          // channel-blocks per batch (384)
__global__ __launch_bounds__(256) void scan_kernel(const float* __restrict__ dT,
                                                   const float* __restrict__ x_dbl,
                                                   const float* __restrict__ uT,
                                                   const float* __restrict__ A_log,
                                                   const float* __restrict__ Dp,
                                                   float* __restrict__ yT) {
  __shared__ float red_all[4][32*66 + 32];
  int tid  = threadIdx.x;
  int wave = tid >> 6;
  int lane = tid & 63;
  float* red = red_all[wave];
  int b = blockIdx.x / CPB;                      // block-uniform -> SGPR
  int c = (blockIdx.x % CPB) * 4 + wave;
  float Ac2 = -__expf(A_log[(size_t)c*64 + lane]) * 1.44269504f;
  float Dc = Dp[c];
  float h = 0.f;
  const float* dp = dT + (size_t)c * NTOK + (size_t)b * SEQL;
  const float* up = uT + (size_t)c * NTOK + (size_t)b * SEQL;
  float* yrow = yT + ((size_t)b*DINNER + c) * SEQL;
  const float* sbase = x_dbl + (size_t)b * SEQL * XDBL_P + DTRANK;  // uniform base

  float d_v = dp[lane];
  float u_v = up[lane];
  int off = lane;                                // 32-bit running element offset

  const int r = lane & 31, hs = lane >> 5;
  const int NBLK = SEQL/64;
  for (int tb = 0; tb < NBLK; ++tb) {
    int t0 = tb*64;
    float d_nxt = 0.f, u_nxt = 0.f;
    if (tb + 1 < NBLK) {
      d_nxt = dp[t0 + 64 + lane];
      u_nxt = up[t0 + 64 + lane];
    }
    float du_v = d_v * u_v;

#pragma unroll
    for (int half = 0; half < 2; ++half) {
#pragma unroll
      for (int k = 0; k < 32; ++k) {
        int i = half*32 + k;
        float Bv = sbase[off];                   // s-base + 32b voff, imm 0
        float Cv = sbase[off + DSTATE];          // same voff, imm +256B
        off += XDBL_P;
        float sd  = readlane_f(d_v,  i);
        float sdu = readlane_f(du_v, i);
        float dA = __builtin_amdgcn_exp2f(sd * Ac2);
        h = fmaf(dA, h, sdu * Bv);
        red[k*66 + lane] = h * Cv;
      }
      {                                          // reduce 32 tokens, 2 lanes/row
        const float2* rp2 = (const float2*)&red[r*66 + hs*32];
        float2 a0 = rp2[0], a1 = rp2[1];
#pragma unroll
        for (int jj = 1; jj < 8; ++jj) {
          float2 v0 = rp2[2*jj], v1 = rp2[2*jj + 1];
          a0.x += v0.x; a0.y += v0.y;
          a1.x += v1.x; a1.y += v1.y;
        }
        float y = (a0.x + a0.y) + (a1.x + a1.y);
        y += __shfl_xor(y, 32);
        float ut = __shfl(u_v, half*32 + r);
        y = fmaf(Dc, ut, y);
        if (lane < 32) yrow[t0 + half*32 + lane] = y;
      }
    }
    __syncthreads();   // phase-lock the 4 waves once per 64 tokens (L1 locality)
    d_v = d_nxt;
    u_v = u_nxt;
  }
}

// ---------------- gate: g[b,t,c] = yT[b,c,t] * silu(z[b,t,c]) -> bf16 (z bf16) ----------------
__global__ __launch_bounds__(256) void ymul_kernel(const float* __restrict__ yT,
                                                   const short* __restrict__ xzq,
                                                   short* __restrict__ g) {
  __shared__ float tile[64][65];
  int b  = blockIdx.z;
  int c0 = blockIdx.x * 64;
  int t0 = blockIdx.y * 64;
  int lx = threadIdx.x & 63;
  int ly = threadIdx.x >> 6;
  const float* src = yT + ((size_t)b*DINNER + c0) * SEQL + t0;
#pragma unroll
  for (int i = 0; i < 16; ++i) {
    int c = ly*16 + i;
    tile[c][lx] = src[(size_t)c*SEQL + lx];
  }
  __syncthreads();
  const int S = 2*DINNER;
#pragma unroll
  for (int i = 0; i < 16; ++i) {
    int t = ly*16 + i;
    float z = bf2f(xzq[((size_t)b*SEQL + t0 + t)*S + DINNER + c0 + lx]);
    float zs = z / (1.f + __expf(-z));
    g[((size_t)b*SEQL + t0 + t)*DINNER + c0 + lx] = f2bf(tile[lx][t] * zs);
  }
}

extern "C" void kernel_launch(void* const* d_in, const int* in_sizes, int n_in,
                              void* d_out, int out_size, void* d_ws, size_t ws_size,
                              hipStream_t stream) {
  const float* x      = (const float*)d_in[0];
  const float* gamma  = (const float*)d_in[1];
  const float* beta   = (const float*)d_in[2];
  const float* W_in   = (const float*)d_in[3];
  const float* conv_w = (const float*)d_in[4];
  const float* conv_b = (const float*)d_in[5];
  const float* W_x    = (const float*)d_in[6];
  const float* W_dt   = (const float*)d_in[7];
  const float* b_dt   = (const float*)d_in[8];
  const float* A_log  = (const float*)d_in[9];
  const float* Dvec   = (const float*)d_in[10];
  const float* W_out  = (const float*)d_in[11];
  float* out = (float*)d_out;

  float* ws = (float*)d_ws;
  float* uT    = ws;                                  // DINNER*NTOK f32
  float* xdbl  = uT    + (size_t)NTOK*1536;           // NTOK*192
  float* dltT  = xdbl  + (size_t)NTOK*XDBL_P;         // DINNER*NTOK
  float* yT    = dltT  + (size_t)NTOK*1536;           // NTOK*1536
  float* xpart = yT    + (size_t)NTOK*1536;           // 4 * NTOK*192
  short* xzq   = (short*)(xpart + (size_t)4*NTOK*XDBL_P);  // NTOK*3072 bf16
  short* xnq   = xzq  + (size_t)NTOK*3072;
  short* ucq   = xnq  + (size_t)NTOK*768;
  short* gq    = ucq  + (size_t)NTOK*1536;
  short* qin   = gq   + (size_t)NTOK*1536;
  short* qx    = qin  + (size_t)NW_IN;
  short* qout  = qx   + (size_t)NW_XP;

  // 1. fused LN + weight conversion
  prep_kernel<<<LN_BLOCKS + (NW_IN+NW_OUT+NW_XP+255)/256, 256, 0, stream>>>(
      x, gamma, beta, xnq, W_in, W_out, W_x, qin, qout, qx);
  // 2. xz = xn @ W_in^T  [2048 x 3072] -> bf16
  gemm_mfma<64,true><<<dim3(3072/64, NTOK/128), 256, 0, stream>>>(
      xnq, qin, (float*)xzq, 3072, DIMD, DIMD, 0);
  // 3. conv + silu (bf16 in) -> ucq bf16, uT f32
  conv_silu_kernel<<<dim3(DINNER/64, SEQL/64, BATCH), 256, 0, stream>>>(
      xzq, conv_w, conv_b, uT, ucq);
  // 4. x_dbl partials, split-K=4
  gemm_mfma<64,false><<<dim3(XDBL_P/64, NTOK/128, 4), 256, 0, stream>>>(
      ucq, qx, xpart, XDBL_P, DINNER, DINNER/4, (size_t)NTOK*XDBL_P);
  reduce4_kernel<<<(NTOK*XDBL_P/4 + 255)/256, 256, 0, stream>>>(xpart, xdbl);
  // 5. deltaT = softplus(W_dt @ dt^T + b_dt)
  gemm_nt<2><<<dim3(NTOK/64, DINNER/64), 256, 0, stream>>>(W_dt, DTRANK, xdbl, XDBL_P, b_dt,
                                                           dltT, NTOK, DINNER, NTOK, DTRANK);
  // 6. selective scan
  scan_kernel<<<BATCH*DINNER/4, 256, 0, stream>>>(dltT, xdbl, uT, A_log, Dvec, yT);
  // 7. gate
  ymul_kernel<<<dim3(DINNER/64, SEQL/64, BATCH), 256, 0, stream>>>(yT, xzq, gq);
  // 8. out = g @ W_out^T
  gemm_mfma<64,false><<<dim3(DIMD/64, NTOK/128), 256, 0, stream>>>(
      gq, qout, out, DIMD, DINNER, DINNER, 0);
}